// Round 6
// baseline (372.578 us; speedup 1.0000x reference)
//
#include <hip/hip_runtime.h>

// Chamfer distance via exact uniform-grid NN search, two-phase queries.
// Grid: 128^3 cells, h=0.1, box [-6.4, 6.4] (all N(0,1) points interior;
// edge cells open-ended in pruning bounds -> conservative even if clamped).
// Pass1 (thread/query, both dirs fused): scan 27-cell neighborhood; final iff
// best <= h^2 (ring>=2 cells are >= h away). Else append (i, best) worklist.
// Pass2 (wave/query, >=1 wave per query): doubling box scan seeded with
// pass1's best. Distance: |y|^2 - 2 q.y (fma chain) + |q|^2 at end (same
// arithmetic as the R2 brute force that scored absmax 0.0).

#define G 128
#define GSH 7
#define CCELLS (G * G * G)      // 2097152
#define H 0.1f
#define INVH 10.0f
#define ORIG (-6.4f)
#define NCHUNK (CCELLS / 256)   // 8192 = 2^13
#define SSTRIDE 2097168u        // ((CCELLS+1)*4 + 63 & ~63)/4 uints

__device__ __forceinline__ int cellcoord(float x) {
    int c = (int)floorf((x - ORIG) * INVH);
    return min(max(c, 0), G - 1);
}
__device__ __forceinline__ int cellof(float x, float y, float z) {
    return (cellcoord(z) << (2 * GSH)) + (cellcoord(y) << GSH) + cellcoord(x);
}
// Conservative axis distance to cell u's extent; edge cells open-ended.
__device__ __forceinline__ float axdist(int u, float qc) {
    float lo = ORIG + u * H;
    float dlo = (u == 0) ? 0.0f : lo - qc;
    float dhi = (u == G - 1) ? 0.0f : qc - (lo + H);
    return fmaxf(0.0f, fmaxf(dlo, dhi));
}

// ---- build pipeline (dual-cloud dispatches) ----
__global__ __launch_bounds__(256) void hist2_kernel(
    const float4* __restrict__ A, const float4* __restrict__ B,
    unsigned int* __restrict__ counts, int n) {
    int i = blockIdx.x * 256 + threadIdx.x;
    const float4* in = blockIdx.y ? B : A;
    unsigned int* c = counts + blockIdx.y * CCELLS;
    if (i < n) {
        float4 a = in[i];
        atomicAdd(&c[cellof(a.x, a.y, a.z)], 1u);
    }
}

__global__ __launch_bounds__(256) void scan_chunk2_kernel(
    const unsigned int* __restrict__ counts, unsigned int* __restrict__ excl,
    unsigned int* __restrict__ blockSums) {
    __shared__ unsigned int lds[256];
    int cb = blockIdx.x & (NCHUNK - 1);
    int b = blockIdx.x >> 13;
    int g = cb * 256 + threadIdx.x;
    unsigned int v = counts[b * CCELLS + g];
    lds[threadIdx.x] = v;
    __syncthreads();
    for (int off = 1; off < 256; off <<= 1) {
        unsigned int t = (threadIdx.x >= off) ? lds[threadIdx.x - off] : 0u;
        __syncthreads();
        lds[threadIdx.x] += t;
        __syncthreads();
    }
    excl[b * SSTRIDE + g] = lds[threadIdx.x] - v;
    if (threadIdx.x == 255) blockSums[blockIdx.x] = lds[255];
}

__global__ __launch_bounds__(256) void scan_sums2_kernel(
    unsigned int* __restrict__ bs0) {
    unsigned int* bs = bs0 + blockIdx.x * NCHUNK;
    __shared__ unsigned int lds[256];
    int t = threadIdx.x;
    unsigned int s = 0;
    for (int k = 0; k < NCHUNK / 256; ++k) s += bs[t * (NCHUNK / 256) + k];
    lds[t] = s;
    __syncthreads();
    for (int off = 1; off < 256; off <<= 1) {
        unsigned int u = (t >= off) ? lds[t - off] : 0u;
        __syncthreads();
        lds[t] += u;
        __syncthreads();
    }
    unsigned int run = lds[t] - s;
    for (int k = 0; k < NCHUNK / 256; ++k) {
        unsigned int v = bs[t * (NCHUNK / 256) + k];
        bs[t * (NCHUNK / 256) + k] = run;
        run += v;
    }
}

// adds chunk offsets AND materializes the scatter cursor array (fused copy)
__global__ __launch_bounds__(256) void add_offsets2_kernel(
    unsigned int* __restrict__ excl, unsigned int* __restrict__ next,
    const unsigned int* __restrict__ bs, int n) {
    int cb = blockIdx.x & (NCHUNK - 1);
    int b = blockIdx.x >> 13;
    int g = cb * 256 + threadIdx.x;
    unsigned int v = excl[b * SSTRIDE + g] + bs[blockIdx.x];
    excl[b * SSTRIDE + g] = v;
    next[b * CCELLS + g] = v;
    if (g == 0) excl[b * SSTRIDE + CCELLS] = (unsigned int)n;
}

__global__ __launch_bounds__(256) void scatter2_kernel(
    const float4* __restrict__ A, const float4* __restrict__ B,
    unsigned int* __restrict__ next, float4* __restrict__ sorted, int n) {
    int i = blockIdx.x * 256 + threadIdx.x;
    const float4* in = blockIdx.y ? B : A;
    unsigned int* nx = next + blockIdx.y * CCELLS;
    float4* out = sorted + blockIdx.y * n;
    if (i < n) {
        float4 a = in[i];
        unsigned int slot = atomicAdd(&nx[cellof(a.x, a.y, a.z)], 1u);
        float s = fmaf(a.x, a.x, fmaf(a.y, a.y, a.z * a.z));
        out[slot] = make_float4(a.x, a.y, a.z, s);
    }
}

// ---- pass 1: 27-cell neighborhood, both directions fused ----
__global__ __launch_bounds__(256) void nn_pass1_kernel(
    const float4* __restrict__ sortedPT, const unsigned int* __restrict__ startPT,
    int n, unsigned int* __restrict__ wlPT, unsigned int* __restrict__ wbPT,
    unsigned int* __restrict__ cnts, double* __restrict__ acc) {
    int dir = blockIdx.y;
    const float4* Q = sortedPT + (size_t)dir * n;
    const float4* pts = sortedPT + (size_t)(1 - dir) * n;
    const unsigned int* start = startPT + (size_t)(1 - dir) * SSTRIDE;
    unsigned int* wl = wlPT + (size_t)dir * n;
    unsigned int* wb = wbPT + (size_t)dir * n;
    unsigned int* cnt = cnts + dir;

    int i = blockIdx.x * 256 + threadIdx.x;
    float v = 0.0f;
    if (i < n) {
        float4 q = Q[i];
        float cx = -2.0f * q.x, cy = -2.0f * q.y, cz = -2.0f * q.z;
        float q2 = q.w;
        int qx = cellcoord(q.x), qy = cellcoord(q.y), qz = cellcoord(q.z);
        int x0 = max(qx - 1, 0), x1 = min(qx + 1, G - 1);
        unsigned int ss[9], ee[9];
        int idx = 0;
#pragma unroll
        for (int dz = -1; dz <= 1; ++dz) {
            int uz = min(max(qz + dz, 0), G - 1);
#pragma unroll
            for (int dy = -1; dy <= 1; ++dy) {
                int uy = min(max(qy + dy, 0), G - 1);
                unsigned int base = ((unsigned)uz << (2 * GSH)) + ((unsigned)uy << GSH);
                ss[idx] = start[base + x0];
                ee[idx] = start[base + x1 + 1];
                ++idx;
            }
        }
        float best = 3.4e38f;
#pragma unroll
        for (int r = 0; r < 9; ++r) {
            unsigned int k = ss[r], e = ee[r];
            for (; k + 2 <= e; k += 2) {
                float4 ya = pts[k];
                float4 yb = pts[k + 1];
                float ea = fmaf(cx, ya.x, fmaf(cy, ya.y, fmaf(cz, ya.z, ya.w)));
                float eb = fmaf(cx, yb.x, fmaf(cy, yb.y, fmaf(cz, yb.z, yb.w)));
                best = fminf(fminf(best, ea), eb);
            }
            if (k < e) {
                float4 ya = pts[k];
                best = fminf(best, fmaf(cx, ya.x, fmaf(cy, ya.y, fmaf(cz, ya.z, ya.w))));
            }
        }
        float ba = q2 + best;
        if (ba <= H * H) {
            v = ba;  // final: no point outside ring 1 can beat h^2
        } else {
            unsigned int w = atomicAdd(cnt, 1u);
            wl[w] = (unsigned int)i;
            wb[w] = __float_as_uint(best);  // relative best handoff
        }
    }
    for (int off = 32; off > 0; off >>= 1) v += __shfl_down(v, off);
    __shared__ float partial[4];
    int lane = threadIdx.x & 63, wid = threadIdx.x >> 6;
    if (lane == 0) partial[wid] = v;
    __syncthreads();
    if (threadIdx.x == 0)
        atomicAdd(acc, (double)((partial[0] + partial[1]) + (partial[2] + partial[3])));
}

// ---- pass 2: one wave per straggler, doubling box scan, both dirs fused ----
__global__ __launch_bounds__(256) void nn_pass2_kernel(
    const float4* __restrict__ sortedPT, const unsigned int* __restrict__ startPT,
    int n, const unsigned int* __restrict__ wlPT, const unsigned int* __restrict__ wbPT,
    const unsigned int* __restrict__ cnts, double* __restrict__ acc) {
    int dir = blockIdx.y;
    const float4* Q = sortedPT + (size_t)dir * n;
    const float4* pts = sortedPT + (size_t)(1 - dir) * n;
    const unsigned int* start = startPT + (size_t)(1 - dir) * SSTRIDE;
    const unsigned int* wl = wlPT + (size_t)dir * n;
    const unsigned int* wb = wbPT + (size_t)dir * n;
    unsigned int m = cnts[dir];

    int lane = threadIdx.x & 63;
    int gwave = (blockIdx.x * 256 + threadIdx.x) >> 6;
    int nwave = gridDim.x * 4;
    float wsum = 0.0f;
    for (unsigned int e = gwave; e < m; e += (unsigned int)nwave) {
        unsigned int qi = wl[e];
        float4 q = Q[qi];
        float cx = -2.0f * q.x, cy = -2.0f * q.y, cz = -2.0f * q.z;
        float q2 = q.w;
        int qx = cellcoord(q.x), qy = cellcoord(q.y), qz = cellcoord(q.z);
        float best = __uint_as_float(wb[e]);  // seeded from pass1
        int Rb = 2;
        for (;;) {
            int z0 = max(qz - Rb, 0), z1 = min(qz + Rb, G - 1);
            int y0 = max(qy - Rb, 0), y1 = min(qy + Rb, G - 1);
            int x0 = max(qx - Rb, 0), x1 = min(qx + Rb, G - 1);
            int nyr = y1 - y0 + 1;
            int nrows = (z1 - z0 + 1) * nyr;
            float lbest = best;
            for (int r = lane; r < nrows; r += 64) {
                int uz = z0 + r / nyr;
                int uy = y0 + r % nyr;
                float dz = axdist(uz, q.z), dy = axdist(uy, q.y);
                float rowd2 = fmaf(dz, dz, dy * dy);
                if (rowd2 >= q2 + lbest) continue;
                unsigned int base = ((unsigned)uz << (2 * GSH)) + ((unsigned)uy << GSH);
                unsigned int k = start[base + x0], ke = start[base + x1 + 1];
                for (; k < ke; ++k) {
                    float4 ya = pts[k];
                    lbest = fminf(lbest,
                        fmaf(cx, ya.x, fmaf(cy, ya.y, fmaf(cz, ya.z, ya.w))));
                }
            }
            for (int off = 32; off > 0; off >>= 1)
                lbest = fminf(lbest, __shfl_xor(lbest, off));
            best = lbest;
            float bnd = (float)Rb * H;
            if (bnd * bnd >= q2 + best || Rb >= G) break;
            Rb = min(Rb * 2, G);
        }
        wsum += q2 + best;
    }
    if (lane == 0 && wsum != 0.0f) atomicAdd(acc, (double)wsum);
}

__global__ void finalize_kernel(const double* __restrict__ acc,
                                float* __restrict__ out, int n) {
    out[0] = (float)(acc[0] / (double)n);
}

// ---- fallback: R2 brute-force (proven, absmax 0.0) ----
#define SPLIT 16
#define PTS 4
__global__ __launch_bounds__(256) void pack_kernel(
    const float4* __restrict__ in, float4* __restrict__ out, int n) {
    int i = blockIdx.x * 256 + threadIdx.x;
    if (i < n) {
        float4 a = in[i];
        float s = fmaf(a.x, a.x, fmaf(a.y, a.y, a.z * a.z));
        out[i] = make_float4(a.x, a.y, a.z, s);
    }
}
__device__ __forceinline__ unsigned int enc_f32(float f) {
    unsigned int u = __float_as_uint(f);
    return (u & 0x80000000u) ? ~u : (u | 0x80000000u);
}
__device__ __forceinline__ float dec_f32(unsigned int u) {
    u = (u & 0x80000000u) ? (u ^ 0x80000000u) : ~u;
    return __uint_as_float(u);
}
__global__ __launch_bounds__(256) void chamfer_dir_kernel(
    const float4* __restrict__ X, const float4* __restrict__ Y,
    int m, unsigned int* __restrict__ mins) {
    int base = blockIdx.x * (256 * PTS) + threadIdx.x;
    float x2x[PTS], x2y[PTS], x2z[PTS], xw[PTS], mn[PTS];
#pragma unroll
    for (int p = 0; p < PTS; ++p) {
        float4 x = X[base + p * 256];
        x2x[p] = -2.0f * x.x; x2y[p] = -2.0f * x.y; x2z[p] = -2.0f * x.z;
        xw[p] = x.w; mn[p] = 3.4e38f;
    }
    int seglen = m / SPLIT, j0 = blockIdx.y * seglen, j1 = j0 + seglen;
    for (int j = j0; j < j1; j += 8) {
#pragma unroll
        for (int u = 0; u < 8; u += 2) {
            float4 ya = Y[j + u];
            float4 yb = Y[j + u + 1];
#pragma unroll
            for (int p = 0; p < PTS; ++p) {
                float ea = fmaf(x2x[p], ya.x, fmaf(x2y[p], ya.y, fmaf(x2z[p], ya.z, ya.w)));
                float eb = fmaf(x2x[p], yb.x, fmaf(x2y[p], yb.y, fmaf(x2z[p], yb.z, yb.w)));
                mn[p] = fminf(fminf(mn[p], ea), eb);
            }
        }
    }
#pragma unroll
    for (int p = 0; p < PTS; ++p)
        atomicMin(&mins[base + p * 256], enc_f32(xw[p] + mn[p]));
}
__global__ __launch_bounds__(256) void reduce_kernel(
    const unsigned int* __restrict__ mins, int total, double* __restrict__ acc) {
    float s = 0.0f;
    for (int i = blockIdx.x * 256 + threadIdx.x; i < total; i += gridDim.x * 256)
        s += dec_f32(mins[i]);
    for (int off = 32; off > 0; off >>= 1) s += __shfl_down(s, off);
    __shared__ float partial[4];
    int lane = threadIdx.x & 63, wid = threadIdx.x >> 6;
    if (lane == 0) partial[wid] = s;
    __syncthreads();
    if (threadIdx.x == 0)
        atomicAdd(acc, (double)((partial[0] + partial[1]) + (partial[2] + partial[3])));
}

extern "C" void kernel_launch(void* const* d_in, const int* in_sizes, int n_in,
                              void* d_out, int out_size, void* d_ws, size_t ws_size,
                              hipStream_t stream) {
    const float4* pred = (const float4*)d_in[0];
    const float4* targ = (const float4*)d_in[1];
    float* out = (float*)d_out;
    int n = in_sizes[0] / 4;  // 131072 points
    int nblk = (n + 255) / 256;

    char* ws = (char*)d_ws;
    double* acc = (double*)ws;                     // [0,8)
    unsigned int* cnts = (unsigned int*)(ws + 8);  // [8,16): cntP, cntT

    size_t startB = (size_t)SSTRIDE * 4;
    size_t needGrid = 64 + 2 * startB + 2ull * CCELLS * 4 + 2ull * n * 16
                    + 4ull * n * 4 + 2ull * NCHUNK * 4;

    if (ws_size >= needGrid && n == 131072) {
        char* p = ws + 64;
        unsigned int* startPT = (unsigned int*)p;  p += 2 * startB;
        unsigned int* nextPT = (unsigned int*)p;   p += 2ull * CCELLS * 4;
        float4* sortedPT = (float4*)p;             p += 2ull * n * 16;
        unsigned int* wlPT = (unsigned int*)p;     p += 2ull * n * 4;
        unsigned int* wbPT = (unsigned int*)p;     p += 2ull * n * 4;
        unsigned int* blockSums = (unsigned int*)p;

        hipMemsetAsync(ws, 0, 16, stream);                       // acc + cnts
        hipMemsetAsync(nextPT, 0, 2ull * CCELLS * 4, stream);    // counts
        hist2_kernel<<<dim3(nblk, 2), 256, 0, stream>>>(pred, targ, nextPT, n);
        scan_chunk2_kernel<<<2 * NCHUNK, 256, 0, stream>>>(nextPT, startPT, blockSums);
        scan_sums2_kernel<<<2, 256, 0, stream>>>(blockSums);
        add_offsets2_kernel<<<2 * NCHUNK, 256, 0, stream>>>(startPT, nextPT, blockSums, n);
        scatter2_kernel<<<dim3(nblk, 2), 256, 0, stream>>>(pred, targ, nextPT, sortedPT, n);

        nn_pass1_kernel<<<dim3(nblk, 2), 256, 0, stream>>>(
            sortedPT, startPT, n, wlPT, wbPT, cnts, acc);
        nn_pass2_kernel<<<dim3(4096, 2), 256, 0, stream>>>(
            sortedPT, startPT, n, wlPT, wbPT, cnts, acc);
    } else {
        hipMemsetAsync(acc, 0, sizeof(double), stream);
        size_t needBF = 64 + 2ull * n * sizeof(float4) + 2ull * n * sizeof(unsigned int);
        if (ws_size >= needBF && (n % (256 * PTS)) == 0 && (n % SPLIT) == 0) {
            float4* P = (float4*)(ws + 64);
            float4* T = P + n;
            unsigned int* minPT = (unsigned int*)(T + n);
            pack_kernel<<<nblk, 256, 0, stream>>>(pred, P, n);
            pack_kernel<<<nblk, 256, 0, stream>>>(targ, T, n);
            hipMemsetAsync(minPT, 0xFF, 2ull * n * sizeof(unsigned int), stream);
            dim3 grid(n / (256 * PTS), SPLIT);
            chamfer_dir_kernel<<<grid, 256, 0, stream>>>(P, T, n, minPT);
            chamfer_dir_kernel<<<grid, 256, 0, stream>>>(T, P, n, minPT + n);
            reduce_kernel<<<256, 256, 0, stream>>>(minPT, 2 * n, acc);
        }
    }
    finalize_kernel<<<1, 1, 0, stream>>>(acc, out, n);
}

// Round 7
// 259.601 us; speedup vs baseline: 1.4352x; 1.4352x over previous
//
#include <hip/hip_runtime.h>

// Chamfer distance via exact uniform-grid NN search, two-phase queries.
// Grid: 128^3 cells, h=0.1, box [-6.4, 6.4] (all N(0,1) points interior).
// Pass1 (thread/query, dirs fused): scan 27-cell neighborhood; final iff
// best <= bound^2 where bound = exact min distance to any UNSCANNED cell
// region (per-axis distance to the 3x3x3 box boundary, in [h, 1.5h]).
// Pass2 (wave/query, ~3.6 queries/wave, moderate concurrency for L2
// locality): doubling box scan that only scans the NEW shell each round
// (inner box already covered by pass1/previous rounds), seeded with pass1's
// best, terminated by the exact box-boundary bound.
// Distance: |y|^2 - 2 q.y (fma chain) + |q|^2 at end (same arithmetic as the
// R2 brute force that scored absmax 0.0).

#define G 128
#define GSH 7
#define CCELLS (G * G * G)      // 2097152
#define H 0.1f
#define INVH 10.0f
#define ORIG (-6.4f)
#define NCHUNK (CCELLS / 256)   // 8192 = 2^13
#define SSTRIDE 2097168u        // ((CCELLS+1)*4 + 63 & ~63)/4 uints
#define INFB 3.4e38f

__device__ __forceinline__ int cellcoord(float x) {
    int c = (int)floorf((x - ORIG) * INVH);
    return min(max(c, 0), G - 1);
}
__device__ __forceinline__ int cellof(float x, float y, float z) {
    return (cellcoord(z) << (2 * GSH)) + (cellcoord(y) << GSH) + cellcoord(x);
}
// Conservative axis distance to cell u's extent; edge cells open-ended.
__device__ __forceinline__ float axdist(int u, float qc) {
    float lo = ORIG + u * H;
    float dlo = (u == 0) ? 0.0f : lo - qc;
    float dhi = (u == G - 1) ? 0.0f : qc - (lo + H);
    return fmaxf(0.0f, fmaxf(dlo, dhi));
}
__device__ __forceinline__ float scan_run(
    const float4* __restrict__ pts, unsigned int k, unsigned int ke,
    float cx, float cy, float cz, float lbest) {
    for (; k < ke; ++k) {
        float4 ya = pts[k];
        lbest = fminf(lbest, fmaf(cx, ya.x, fmaf(cy, ya.y, fmaf(cz, ya.z, ya.w))));
    }
    return lbest;
}

// ---- build pipeline (dual-cloud dispatches) ----
__global__ __launch_bounds__(256) void hist2_kernel(
    const float4* __restrict__ A, const float4* __restrict__ B,
    unsigned int* __restrict__ counts, int n) {
    int i = blockIdx.x * 256 + threadIdx.x;
    const float4* in = blockIdx.y ? B : A;
    unsigned int* c = counts + blockIdx.y * CCELLS;
    if (i < n) {
        float4 a = in[i];
        atomicAdd(&c[cellof(a.x, a.y, a.z)], 1u);
    }
}

__global__ __launch_bounds__(256) void scan_chunk2_kernel(
    const unsigned int* __restrict__ counts, unsigned int* __restrict__ excl,
    unsigned int* __restrict__ blockSums) {
    __shared__ unsigned int lds[256];
    int cb = blockIdx.x & (NCHUNK - 1);
    int b = blockIdx.x >> 13;
    int g = cb * 256 + threadIdx.x;
    unsigned int v = counts[b * CCELLS + g];
    lds[threadIdx.x] = v;
    __syncthreads();
    for (int off = 1; off < 256; off <<= 1) {
        unsigned int t = (threadIdx.x >= off) ? lds[threadIdx.x - off] : 0u;
        __syncthreads();
        lds[threadIdx.x] += t;
        __syncthreads();
    }
    excl[b * SSTRIDE + g] = lds[threadIdx.x] - v;
    if (threadIdx.x == 255) blockSums[blockIdx.x] = lds[255];
}

__global__ __launch_bounds__(256) void scan_sums2_kernel(
    unsigned int* __restrict__ bs0) {
    unsigned int* bs = bs0 + blockIdx.x * NCHUNK;
    __shared__ unsigned int lds[256];
    int t = threadIdx.x;
    unsigned int s = 0;
    for (int k = 0; k < NCHUNK / 256; ++k) s += bs[t * (NCHUNK / 256) + k];
    lds[t] = s;
    __syncthreads();
    for (int off = 1; off < 256; off <<= 1) {
        unsigned int u = (t >= off) ? lds[t - off] : 0u;
        __syncthreads();
        lds[t] += u;
        __syncthreads();
    }
    unsigned int run = lds[t] - s;
    for (int k = 0; k < NCHUNK / 256; ++k) {
        unsigned int v = bs[t * (NCHUNK / 256) + k];
        bs[t * (NCHUNK / 256) + k] = run;
        run += v;
    }
}

// adds chunk offsets AND materializes the scatter cursor array (fused copy)
__global__ __launch_bounds__(256) void add_offsets2_kernel(
    unsigned int* __restrict__ excl, unsigned int* __restrict__ next,
    const unsigned int* __restrict__ bs, int n) {
    int cb = blockIdx.x & (NCHUNK - 1);
    int b = blockIdx.x >> 13;
    int g = cb * 256 + threadIdx.x;
    unsigned int v = excl[b * SSTRIDE + g] + bs[blockIdx.x];
    excl[b * SSTRIDE + g] = v;
    next[b * CCELLS + g] = v;
    if (g == 0) excl[b * SSTRIDE + CCELLS] = (unsigned int)n;
}

__global__ __launch_bounds__(256) void scatter2_kernel(
    const float4* __restrict__ A, const float4* __restrict__ B,
    unsigned int* __restrict__ next, float4* __restrict__ sorted, int n) {
    int i = blockIdx.x * 256 + threadIdx.x;
    const float4* in = blockIdx.y ? B : A;
    unsigned int* nx = next + blockIdx.y * CCELLS;
    float4* out = sorted + blockIdx.y * n;
    if (i < n) {
        float4 a = in[i];
        unsigned int slot = atomicAdd(&nx[cellof(a.x, a.y, a.z)], 1u);
        float s = fmaf(a.x, a.x, fmaf(a.y, a.y, a.z * a.z));
        out[slot] = make_float4(a.x, a.y, a.z, s);
    }
}

// ---- pass 1: 27-cell neighborhood, both directions fused ----
__global__ __launch_bounds__(256) void nn_pass1_kernel(
    const float4* __restrict__ sortedPT, const unsigned int* __restrict__ startPT,
    int n, unsigned int* __restrict__ wlPT, unsigned int* __restrict__ wbPT,
    unsigned int* __restrict__ cnts, double* __restrict__ acc) {
    int dir = blockIdx.y;
    const float4* Q = sortedPT + (size_t)dir * n;
    const float4* pts = sortedPT + (size_t)(1 - dir) * n;
    const unsigned int* start = startPT + (size_t)(1 - dir) * SSTRIDE;
    unsigned int* wl = wlPT + (size_t)dir * n;
    unsigned int* wb = wbPT + (size_t)dir * n;
    unsigned int* cnt = cnts + dir;

    int i = blockIdx.x * 256 + threadIdx.x;
    float v = 0.0f;
    if (i < n) {
        float4 q = Q[i];
        float cx = -2.0f * q.x, cy = -2.0f * q.y, cz = -2.0f * q.z;
        float q2 = q.w;
        int qx = cellcoord(q.x), qy = cellcoord(q.y), qz = cellcoord(q.z);
        int x0 = max(qx - 1, 0), x1 = min(qx + 1, G - 1);
        unsigned int ss[9], ee[9];
        int idx = 0;
#pragma unroll
        for (int dz = -1; dz <= 1; ++dz) {
            int uz = min(max(qz + dz, 0), G - 1);
#pragma unroll
            for (int dy = -1; dy <= 1; ++dy) {
                int uy = min(max(qy + dy, 0), G - 1);
                unsigned int base = ((unsigned)uz << (2 * GSH)) + ((unsigned)uy << GSH);
                ss[idx] = start[base + x0];
                ee[idx] = start[base + x1 + 1];
                ++idx;
            }
        }
        float best = 3.4e38f;
#pragma unroll
        for (int r = 0; r < 9; ++r) {
            unsigned int k = ss[r], e = ee[r];
            for (; k + 2 <= e; k += 2) {
                float4 ya = pts[k];
                float4 yb = pts[k + 1];
                float ea = fmaf(cx, ya.x, fmaf(cy, ya.y, fmaf(cz, ya.z, ya.w)));
                float eb = fmaf(cx, yb.x, fmaf(cy, yb.y, fmaf(cz, yb.z, yb.w)));
                best = fminf(fminf(best, ea), eb);
            }
            if (k < e) {
                float4 ya = pts[k];
                best = fminf(best, fmaf(cx, ya.x, fmaf(cy, ya.y, fmaf(cz, ya.z, ya.w))));
            }
        }
        float ba = q2 + best;
        // exact finality bound: min distance from q to any unscanned cell.
        // unscanned below on axis needs cells <= q-2 to exist, etc.
        float fx = q.x - (ORIG + (float)qx * H);  // offset in cell, ~[0,H)
        float fy = q.y - (ORIG + (float)qy * H);
        float fz = q.z - (ORIG + (float)qz * H);
        float bx = fminf((qx >= 2) ? (fx + H) : INFB,
                         (qx <= G - 3) ? (2.0f * H - fx) : INFB);
        float by = fminf((qy >= 2) ? (fy + H) : INFB,
                         (qy <= G - 3) ? (2.0f * H - fy) : INFB);
        float bz = fminf((qz >= 2) ? (fz + H) : INFB,
                         (qz <= G - 3) ? (2.0f * H - fz) : INFB);
        float bound = fminf(bx, fminf(by, bz)) * 0.99999f;  // ulp safety
        if (ba <= bound * bound) {
            v = ba;  // final: no unscanned point can beat it
        } else {
            unsigned int w = atomicAdd(cnt, 1u);
            wl[w] = (unsigned int)i;
            wb[w] = __float_as_uint(best);  // relative best handoff
        }
    }
    for (int off = 32; off > 0; off >>= 1) v += __shfl_down(v, off);
    __shared__ float partial[4];
    int lane = threadIdx.x & 63, wid = threadIdx.x >> 6;
    if (lane == 0) partial[wid] = v;
    __syncthreads();
    if (threadIdx.x == 0)
        atomicAdd(acc, (double)((partial[0] + partial[1]) + (partial[2] + partial[3])));
}

// ---- pass 2: wave/query, shell-only doubling scan, both dirs fused ----
__global__ __launch_bounds__(256) void nn_pass2_kernel(
    const float4* __restrict__ sortedPT, const unsigned int* __restrict__ startPT,
    int n, const unsigned int* __restrict__ wlPT, const unsigned int* __restrict__ wbPT,
    const unsigned int* __restrict__ cnts, double* __restrict__ acc) {
    int dir = blockIdx.y;
    const float4* Q = sortedPT + (size_t)dir * n;
    const float4* pts = sortedPT + (size_t)(1 - dir) * n;
    const unsigned int* start = startPT + (size_t)(1 - dir) * SSTRIDE;
    const unsigned int* wl = wlPT + (size_t)dir * n;
    const unsigned int* wb = wbPT + (size_t)dir * n;
    unsigned int m = cnts[dir];

    int lane = threadIdx.x & 63;
    int gwave = (blockIdx.x * 256 + threadIdx.x) >> 6;
    int nwave = gridDim.x * 4;
    float wsum = 0.0f;
    for (unsigned int e = gwave; e < m; e += (unsigned int)nwave) {
        unsigned int qi = wl[e];
        float4 q = Q[qi];
        float cx = -2.0f * q.x, cy = -2.0f * q.y, cz = -2.0f * q.z;
        float q2 = q.w;
        int qx = cellcoord(q.x), qy = cellcoord(q.y), qz = cellcoord(q.z);
        float fx = q.x - (ORIG + (float)qx * H);
        float fy = q.y - (ORIG + (float)qy * H);
        float fz = q.z - (ORIG + (float)qz * H);
        float best = __uint_as_float(wb[e]);  // seeded from pass1 (ring<=1)
        int Rp = 1;   // rings <= Rp already covered (pass1's 27-cell box)
        int Rb = 2;
        for (;;) {
            int z0 = max(qz - Rb, 0), z1 = min(qz + Rb, G - 1);
            int y0 = max(qy - Rb, 0), y1 = min(qy + Rb, G - 1);
            int x0 = max(qx - Rb, 0), x1 = min(qx + Rb, G - 1);
            int nyr = y1 - y0 + 1;
            int nrows = (z1 - z0 + 1) * nyr;
            float lbest = best;
            for (int r = lane; r < nrows; r += 64) {
                int uz = z0 + r / nyr;
                int uy = y0 + r % nyr;
                int az = uz > qz ? uz - qz : qz - uz;
                int ay = uy > qy ? uy - qy : qy - uy;
                float dz = axdist(uz, q.z), dy = axdist(uy, q.y);
                float rowd2 = fmaf(dz, dz, dy * dy);
                if (rowd2 >= q2 + lbest) continue;
                unsigned int base = ((unsigned)uz << (2 * GSH)) + ((unsigned)uy << GSH);
                if (az <= Rp && ay <= Rp) {
                    // inner-row: only x beyond the covered box is new
                    int xa1 = qx - Rp - 1;
                    int xb0 = qx + Rp + 1;
                    if (xa1 >= x0)
                        lbest = scan_run(pts, start[base + x0], start[base + xa1 + 1],
                                         cx, cy, cz, lbest);
                    if (xb0 <= x1)
                        lbest = scan_run(pts, start[base + xb0], start[base + x1 + 1],
                                         cx, cy, cz, lbest);
                } else {
                    lbest = scan_run(pts, start[base + x0], start[base + x1 + 1],
                                     cx, cy, cz, lbest);
                }
            }
            for (int off = 32; off > 0; off >>= 1)
                lbest = fminf(lbest, __shfl_xor(lbest, off));
            best = lbest;
            // exact termination: min distance from q to any cell outside +-Rb
            float bx = fminf((qx - Rb >= 1) ? fmaf((float)Rb, H, fx) : INFB,
                             (qx + Rb + 1 <= G - 1) ? ((float)(Rb + 1) * H - fx) : INFB);
            float by = fminf((qy - Rb >= 1) ? fmaf((float)Rb, H, fy) : INFB,
                             (qy + Rb + 1 <= G - 1) ? ((float)(Rb + 1) * H - fy) : INFB);
            float bz = fminf((qz - Rb >= 1) ? fmaf((float)Rb, H, fz) : INFB,
                             (qz + Rb + 1 <= G - 1) ? ((float)(Rb + 1) * H - fz) : INFB);
            float bound = fminf(bx, fminf(by, bz)) * 0.99999f;
            if (q2 + best <= bound * bound || Rb >= G) break;
            Rp = Rb;
            Rb = min(Rb * 2, G);
        }
        wsum += q2 + best;
    }
    if (lane == 0 && wsum != 0.0f) atomicAdd(acc, (double)wsum);
}

__global__ void finalize_kernel(const double* __restrict__ acc,
                                float* __restrict__ out, int n) {
    out[0] = (float)(acc[0] / (double)n);
}

// ---- fallback: R2 brute-force (proven, absmax 0.0) ----
#define SPLIT 16
#define PTS 4
__global__ __launch_bounds__(256) void pack_kernel(
    const float4* __restrict__ in, float4* __restrict__ out, int n) {
    int i = blockIdx.x * 256 + threadIdx.x;
    if (i < n) {
        float4 a = in[i];
        float s = fmaf(a.x, a.x, fmaf(a.y, a.y, a.z * a.z));
        out[i] = make_float4(a.x, a.y, a.z, s);
    }
}
__device__ __forceinline__ unsigned int enc_f32(float f) {
    unsigned int u = __float_as_uint(f);
    return (u & 0x80000000u) ? ~u : (u | 0x80000000u);
}
__device__ __forceinline__ float dec_f32(unsigned int u) {
    u = (u & 0x80000000u) ? (u ^ 0x80000000u) : ~u;
    return __uint_as_float(u);
}
__global__ __launch_bounds__(256) void chamfer_dir_kernel(
    const float4* __restrict__ X, const float4* __restrict__ Y,
    int m, unsigned int* __restrict__ mins) {
    int base = blockIdx.x * (256 * PTS) + threadIdx.x;
    float x2x[PTS], x2y[PTS], x2z[PTS], xw[PTS], mn[PTS];
#pragma unroll
    for (int p = 0; p < PTS; ++p) {
        float4 x = X[base + p * 256];
        x2x[p] = -2.0f * x.x; x2y[p] = -2.0f * x.y; x2z[p] = -2.0f * x.z;
        xw[p] = x.w; mn[p] = 3.4e38f;
    }
    int seglen = m / SPLIT, j0 = blockIdx.y * seglen, j1 = j0 + seglen;
    for (int j = j0; j < j1; j += 8) {
#pragma unroll
        for (int u = 0; u < 8; u += 2) {
            float4 ya = Y[j + u];
            float4 yb = Y[j + u + 1];
#pragma unroll
            for (int p = 0; p < PTS; ++p) {
                float ea = fmaf(x2x[p], ya.x, fmaf(x2y[p], ya.y, fmaf(x2z[p], ya.z, ya.w)));
                float eb = fmaf(x2x[p], yb.x, fmaf(x2y[p], yb.y, fmaf(x2z[p], yb.z, yb.w)));
                mn[p] = fminf(fminf(mn[p], ea), eb);
            }
        }
    }
#pragma unroll
    for (int p = 0; p < PTS; ++p)
        atomicMin(&mins[base + p * 256], enc_f32(xw[p] + mn[p]));
}
__global__ __launch_bounds__(256) void reduce_kernel(
    const unsigned int* __restrict__ mins, int total, double* __restrict__ acc) {
    float s = 0.0f;
    for (int i = blockIdx.x * 256 + threadIdx.x; i < total; i += gridDim.x * 256)
        s += dec_f32(mins[i]);
    for (int off = 32; off > 0; off >>= 1) s += __shfl_down(s, off);
    __shared__ float partial[4];
    int lane = threadIdx.x & 63, wid = threadIdx.x >> 6;
    if (lane == 0) partial[wid] = s;
    __syncthreads();
    if (threadIdx.x == 0)
        atomicAdd(acc, (double)((partial[0] + partial[1]) + (partial[2] + partial[3])));
}

extern "C" void kernel_launch(void* const* d_in, const int* in_sizes, int n_in,
                              void* d_out, int out_size, void* d_ws, size_t ws_size,
                              hipStream_t stream) {
    const float4* pred = (const float4*)d_in[0];
    const float4* targ = (const float4*)d_in[1];
    float* out = (float*)d_out;
    int n = in_sizes[0] / 4;  // 131072 points
    int nblk = (n + 255) / 256;

    char* ws = (char*)d_ws;
    double* acc = (double*)ws;                     // [0,8)
    unsigned int* cnts = (unsigned int*)(ws + 8);  // [8,16): cntP, cntT

    size_t startB = (size_t)SSTRIDE * 4;
    size_t needGrid = 64 + 2 * startB + 2ull * CCELLS * 4 + 2ull * n * 16
                    + 4ull * n * 4 + 2ull * NCHUNK * 4;

    if (ws_size >= needGrid && n == 131072) {
        char* p = ws + 64;
        unsigned int* startPT = (unsigned int*)p;  p += 2 * startB;
        unsigned int* nextPT = (unsigned int*)p;   p += 2ull * CCELLS * 4;
        float4* sortedPT = (float4*)p;             p += 2ull * n * 16;
        unsigned int* wlPT = (unsigned int*)p;     p += 2ull * n * 4;
        unsigned int* wbPT = (unsigned int*)p;     p += 2ull * n * 4;
        unsigned int* blockSums = (unsigned int*)p;

        hipMemsetAsync(ws, 0, 16, stream);                       // acc + cnts
        hipMemsetAsync(nextPT, 0, 2ull * CCELLS * 4, stream);    // counts
        hist2_kernel<<<dim3(nblk, 2), 256, 0, stream>>>(pred, targ, nextPT, n);
        scan_chunk2_kernel<<<2 * NCHUNK, 256, 0, stream>>>(nextPT, startPT, blockSums);
        scan_sums2_kernel<<<2, 256, 0, stream>>>(blockSums);
        add_offsets2_kernel<<<2 * NCHUNK, 256, 0, stream>>>(startPT, nextPT, blockSums, n);
        scatter2_kernel<<<dim3(nblk, 2), 256, 0, stream>>>(pred, targ, nextPT, sortedPT, n);

        nn_pass1_kernel<<<dim3(nblk, 2), 256, 0, stream>>>(
            sortedPT, startPT, n, wlPT, wbPT, cnts, acc);
        nn_pass2_kernel<<<dim3(512, 2), 256, 0, stream>>>(
            sortedPT, startPT, n, wlPT, wbPT, cnts, acc);
    } else {
        hipMemsetAsync(acc, 0, sizeof(double), stream);
        size_t needBF = 64 + 2ull * n * sizeof(float4) + 2ull * n * sizeof(unsigned int);
        if (ws_size >= needBF && (n % (256 * PTS)) == 0 && (n % SPLIT) == 0) {
            float4* P = (float4*)(ws + 64);
            float4* T = P + n;
            unsigned int* minPT = (unsigned int*)(T + n);
            pack_kernel<<<nblk, 256, 0, stream>>>(pred, P, n);
            pack_kernel<<<nblk, 256, 0, stream>>>(targ, T, n);
            hipMemsetAsync(minPT, 0xFF, 2ull * n * sizeof(unsigned int), stream);
            dim3 grid(n / (256 * PTS), SPLIT);
            chamfer_dir_kernel<<<grid, 256, 0, stream>>>(P, T, n, minPT);
            chamfer_dir_kernel<<<grid, 256, 0, stream>>>(T, P, n, minPT + n);
            reduce_kernel<<<256, 256, 0, stream>>>(minPT, 2 * n, acc);
        }
    }
    finalize_kernel<<<1, 1, 0, stream>>>(acc, out, n);
}